// Round 8
// baseline (232.805 us; speedup 1.0000x reference)
//
#include <hip/hip_runtime.h>
#include <hip/hip_fp16.h>
#include <math.h>

#define N_NODES 20000
#define N_EDGES 160000
#define EPSV 1e-12f
#define SLOPE 0.2f
#define LOG2E 1.4426950408889634f

__device__ __forceinline__ float leaky(float x) { return x >= 0.f ? x : SLOPE * x; }

__device__ __forceinline__ unsigned short cvt_bf16(float f) {
    unsigned u = __float_as_uint(f);
    u = (u + 0x7FFFu + ((u >> 16) & 1u)) >> 16;
    return (unsigned short)u;
}
__device__ __forceinline__ unsigned pk2(float a, float b) {
    return (unsigned)cvt_bf16(a) | ((unsigned)cvt_bf16(b) << 16);
}

// fragment-ordered Bt index: column n (0..319), k (0..255)
__device__ __forceinline__ int btf_idx(int n, int k) {
    int w = n / 80, rem = n - w * 80, t = rem >> 4, l16 = rem & 15;
    int kk = k >> 5, c = k & 31, quad = c >> 3, e = c & 7;
    int lane = quad * 16 + l16;
    return (((w * 5 + t) * 8 + kk) * 64 + lane) * 8 + e;
}

typedef __attribute__((ext_vector_type(8))) short bf16x8;
typedef __attribute__((ext_vector_type(8))) _Float16 f16x8;
typedef __attribute__((ext_vector_type(4))) float f32x4;

// ============ STAGE 1: fold (0..271) + rel (272) + count (273..912) + Wp pack (913) ============
__global__ __launch_bounds__(256) void k_pre(
    const float* __restrict__ Wv, const float* __restrict__ Wn,
    const float* __restrict__ nbb, const float* __restrict__ wsrc,
    const float* __restrict__ wtgt, const float* __restrict__ gw,
    unsigned short* __restrict__ Btf, float* __restrict__ bg2,
    const float* __restrict__ Wrel, const float* __restrict__ wrel,
    const float* __restrict__ deprel_emb, const float* __restrict__ deparc_emb,
    float* __restrict__ SA, float* __restrict__ SB,
    const int* __restrict__ tgt, int* __restrict__ cnts,
    const float* __restrict__ fpw, __half* __restrict__ Wpf,
    int* __restrict__ rss)
{
    __shared__ float wr2[128 * 8];
    __shared__ int cnt[250];
    __shared__ float gwc[256];
    __shared__ int wtot[4];
    int k = threadIdx.x;
    int b = blockIdx.x;
    if (b < 256) {
        Btf[btf_idx(b, k)] = cvt_bf16(Wv[k * 256 + b]);
    } else if (b < 264) {
        int h = b - 256;
        // stage gw column h (rows 256..511) once: kills 256 stride-8 gathers/thread
        gwc[k] = gw[(256 + k) * 8 + h];
        __syncthreads();
        float a_vs = 0.f, a_vt = 0.f, a_ng = 0.f;
        for (int d = 0; d < 32; ++d) {
            float w = Wv[k * 256 + h * 32 + d];
            a_vs = fmaf(w, wsrc[h * 32 + d], a_vs);
            a_vt = fmaf(w, wtgt[h * 32 + d], a_vt);
        }
        const float4* wn4 = (const float4*)(Wn + (size_t)k * 256);
#pragma unroll 4
        for (int j = 0; j < 64; ++j) {
            float4 w4 = wn4[j];
            a_ng = fmaf(w4.x, gwc[j * 4 + 0], a_ng);
            a_ng = fmaf(w4.y, gwc[j * 4 + 1], a_ng);
            a_ng = fmaf(w4.z, gwc[j * 4 + 2], a_ng);
            a_ng = fmaf(w4.w, gwc[j * 4 + 3], a_ng);
        }
        Btf[btf_idx(256 + h, k)] = cvt_bf16(a_vs);
        Btf[btf_idx(264 + h, k)] = cvt_bf16(a_vt);
        Btf[btf_idx(272 + h, k)] = cvt_bf16(gw[k * 8 + h]);
        Btf[btf_idx(280 + h, k)] = cvt_bf16(a_ng);
        // bg2[h] = nbb . gwc, block-parallel reduce (reuse wr2 as scratch)
        wr2[k] = nbb[k] * gwc[k];
        __syncthreads();
        if (k < 64) {
            float t = wr2[k] + wr2[k + 64] + wr2[k + 128] + wr2[k + 192];
#pragma unroll
            for (int off = 32; off; off >>= 1) t += __shfl_down(t, off, 64);
            if (k == 0) bg2[h] = t;
        }
    } else if (b < 272) {
        int n0 = 288 + (b - 264) * 4;
        for (int i = 0; i < 4; ++i) Btf[btf_idx(n0 + i, k)] = 0;
    } else if (b == 272) {
        for (int i = k; i < 1024; i += 256) {
            int kk = i >> 3, h = i & 7;
            float acc = 0.f;
            for (int r = 0; r < 16; ++r)
                acc += Wrel[kk * 128 + h * 16 + r] * wrel[h * 16 + r];
            wr2[kk * 8 + h] = acc;
        }
        __syncthreads();
        for (int i = k; i < 50 * 8; i += 256) {
            int d = i >> 3, h = i & 7;
            float acc = 0.f;
            for (int kk = 0; kk < 64; ++kk) acc += deprel_emb[d * 64 + kk] * wr2[kk * 8 + h];
            SA[i] = acc;
        }
        for (int i = k; i < 4 * 8; i += 256) {
            int d = i >> 3, h = i & 7;
            float acc = 0.f;
            for (int kk = 0; kk < 64; ++kk) acc += deparc_emb[d * 64 + kk] * wr2[(64 + kk) * 8 + h];
            SB[i] = acc;
        }
    } else if (b < 913) {
        int idx = b - 273;
        int slice = idx & 7, range = idx >> 3;
        int lo = range * 250;
        if (k < 250) cnt[k] = 0;
        __syncthreads();
        const int4* t4 = (const int4*)tgt;
        int i0 = slice * 5000;
        int mc = 0;   // per-thread match count -> block total -> rss[(range,slice)]
#pragma unroll 4
        for (int i = k; i < 5000; i += 256) {
            int4 v = t4[i0 + i];
            unsigned a = (unsigned)(v.x - lo); if (a < 250u) { atomicAdd(&cnt[a], 1); ++mc; }
            unsigned bb = (unsigned)(v.y - lo); if (bb < 250u) { atomicAdd(&cnt[bb], 1); ++mc; }
            unsigned c = (unsigned)(v.z - lo); if (c < 250u) { atomicAdd(&cnt[c], 1); ++mc; }
            unsigned d = (unsigned)(v.w - lo); if (d < 250u) { atomicAdd(&cnt[d], 1); ++mc; }
        }
        __syncthreads();
        if (k < 250) cnts[(lo + k) * 8 + slice] = cnt[k];
#pragma unroll
        for (int off = 32; off; off >>= 1) mc += __shfl_down(mc, off, 64);
        if ((k & 63) == 0) wtot[k >> 6] = mc;
        __syncthreads();
        if (k == 0) rss[idx] = wtot[0] + wtot[1] + wtot[2] + wtot[3];
    } else {
        // pack final_proj_w into f16 MFMA B-fragments:
        // Wpf[((h*2+jt)*2+kp)*64 + lane][e] = Wp[h][kp*32 + (lane>>4)*8 + e][jt*16 + (lane&15)]
        for (int i = k; i < 2048; i += 256) {
            int lane = i & 63, kp = (i >> 6) & 1, jt = (i >> 7) & 1, h = i >> 8;
            int col = jt * 16 + (lane & 15);
            int krow = kp * 32 + (lane >> 4) * 8;
#pragma unroll
            for (int e = 0; e < 8; ++e)
                Wpf[(size_t)i * 8 + e] = __float2half(fpw[h * 2048 + (krow + e) * 32 + col]);
        }
    }
}

// ============ STAGE 2: mfma (0..1249) + parallel range scans (1250..1329) ============
__global__ __launch_bounds__(256) void k_mid(
    const float* __restrict__ inp, const unsigned short* __restrict__ Btf,
    const float* __restrict__ bg2, __half* __restrict__ valh,
    float* __restrict__ vs, float* __restrict__ vt,
    float* __restrict__ g1, float* __restrict__ g2,
    const int* __restrict__ cnts, const int* __restrict__ rss,
    int* __restrict__ rowptr)
{
    __shared__ int red[4], red2[4];
    int tid = threadIdx.x;
    if (blockIdx.x < 1250) {
        int wave = tid >> 6, lane = tid & 63;
        int quad = lane >> 4, l16 = lane & 15;
        int row0 = blockIdx.x * 16;
        const float* arow = inp + (size_t)(row0 + l16) * 256;
        bf16x8 afr[8];
#pragma unroll
        for (int kk = 0; kk < 8; ++kk) {
            float4 f0 = *(const float4*)(arow + kk * 32 + quad * 8);
            float4 f1 = *(const float4*)(arow + kk * 32 + quad * 8 + 4);
            union { unsigned u[4]; bf16x8 v; } cv;
            cv.u[0] = pk2(f0.x, f0.y); cv.u[1] = pk2(f0.z, f0.w);
            cv.u[2] = pk2(f1.x, f1.y); cv.u[3] = pk2(f1.z, f1.w);
            afr[kk] = cv.v;
        }
        f32x4 acc[5] = {};
#pragma unroll
        for (int kk = 0; kk < 8; ++kk) {
#pragma unroll
            for (int t = 0; t < 5; ++t) {
                bf16x8 bf = *(const bf16x8*)(Btf + (((wave * 5 + t) * 8 + kk) * 64 + lane) * 8);
                acc[t] = __builtin_amdgcn_mfma_f32_16x16x32_bf16(afr[kk], bf, acc[t], 0, 0, 0);
            }
        }
#pragma unroll
        for (int t = 0; t < 5; ++t) {
            int n = wave * 80 + t * 16 + l16;
#pragma unroll
            for (int r = 0; r < 4; ++r) {
                int row = row0 + quad * 4 + r;
                float v = acc[t][r];
                if (n < 256) {
                    valh[(size_t)row * 256 + n] = __float2half(v);
                } else if (n < 288) {
                    int c2 = n - 256, which = c2 >> 3, h = c2 & 7;
                    if (which == 3) v += bg2[h];
                    float* dst = (which == 0) ? vs : (which == 1) ? vt : (which == 2) ? g1 : g2;
                    dst[(size_t)row * 8 + h] = v;
                }
            }
        }
    } else {
        int r = blockIdx.x - 1250;       // range 0..79
        int lo = r * 250;
        int lane = tid & 63, w = tid >> 6;
        // base = number of edges landing in ranges < r
        int m = r * 8;
        int part = 0;
        for (int i = tid; i < m; i += 256) part += rss[i];
#pragma unroll
        for (int off = 32; off; off >>= 1) part += __shfl_down(part, off, 64);
        if (lane == 0) red[w] = part;
        // local degree of node lo+tid
        int deg = 0;
        if (tid < 250) {
            const int4* c4 = (const int4*)(cnts + (size_t)(lo + tid) * 8);
            int4 a = c4[0], b2 = c4[1];
            deg = a.x + a.y + a.z + a.w + b2.x + b2.y + b2.z + b2.w;
        }
        int ps = deg;
#pragma unroll
        for (int off = 1; off < 64; off <<= 1) {
            int x = __shfl_up(ps, off, 64);
            if (lane >= off) ps += x;
        }
        if (lane == 63) red2[w] = ps;
        __syncthreads();
        int base = red[0] + red[1] + red[2] + red[3];
        int wo = 0;
        for (int i = 0; i < w; ++i) wo += red2[i];
        if (tid < 250) rowptr[lo + tid] = base + wo + ps - deg;
        if (r == 79 && tid == 0) rowptr[N_NODES] = N_EDGES;
    }
}

// ============ STAGE 3: fill CSR src index + per-edge f32 score records ============
// esc[p][0..7]  = vs[src]           (value-score row)
// esc[p][8..15] = SA[dr] + SB[da]   (relation-score row, pre-summed)
// esc[p][16..23]= g2[src]           (gate contribution row)
__device__ __forceinline__ void fill_rec(
    int p, int s, int dr, int da,
    int* __restrict__ eidx, float* __restrict__ esc,
    const float* __restrict__ vs, const float* __restrict__ SA,
    const float* __restrict__ SB, const float* __restrict__ g2)
{
    eidx[p] = s;
    float* ep = esc + (size_t)p * 24;
    const float4* vp = (const float4*)(vs + (size_t)s * 8);
    const float4* ap = (const float4*)(SA + dr * 8);
    const float4* bp = (const float4*)(SB + da * 8);
    const float4* gp = (const float4*)(g2 + (size_t)s * 8);
    float4 v0 = vp[0], v1 = vp[1];
    float4 a0 = ap[0], a1 = ap[1];
    float4 b0 = bp[0], b1 = bp[1];
    float4 g0 = gp[0], g1v = gp[1];
    ((float4*)ep)[0] = v0;
    ((float4*)ep)[1] = v1;
    ((float4*)ep)[2] = make_float4(a0.x + b0.x, a0.y + b0.y, a0.z + b0.z, a0.w + b0.w);
    ((float4*)ep)[3] = make_float4(a1.x + b1.x, a1.y + b1.y, a1.z + b1.z, a1.w + b1.w);
    ((float4*)ep)[4] = g0;
    ((float4*)ep)[5] = g1v;
}

__global__ __launch_bounds__(256) void k_fill(
    const int* __restrict__ src, const int* __restrict__ tgt,
    const int* __restrict__ deprel, const int* __restrict__ deparc,
    const int* __restrict__ rowptr, const int* __restrict__ cnts,
    const float* __restrict__ vs, const float* __restrict__ SA,
    const float* __restrict__ SB, const float* __restrict__ g2,
    int* __restrict__ eidx, float* __restrict__ esc)
{
    __shared__ int cur[250];
    int tid = threadIdx.x;
    int slice = blockIdx.x & 7, range = blockIdx.x >> 3;
    int lo = range * 250;
    if (tid < 250) {
        int base = rowptr[lo + tid];
        const int* c = cnts + (size_t)(lo + tid) * 8;
        for (int s = 0; s < slice; ++s) base += c[s];
        cur[tid] = base;
    }
    __syncthreads();
    const int4* t4 = (const int4*)tgt;
    const int4* s4 = (const int4*)src;
    const int4* r4 = (const int4*)deprel;
    const int4* a4 = (const int4*)deparc;
    int i0 = slice * 5000;
    for (int i = tid; i < 5000; i += 256) {
        int4 v = t4[i0 + i];
        int4 sv = s4[i0 + i];
        int4 rv = r4[i0 + i];
        int4 av = a4[i0 + i];
        unsigned a = (unsigned)(v.x - lo); if (a < 250u) { int p = atomicAdd(&cur[a], 1); fill_rec(p, sv.x, rv.x, av.x, eidx, esc, vs, SA, SB, g2); }
        unsigned b = (unsigned)(v.y - lo); if (b < 250u) { int p = atomicAdd(&cur[b], 1); fill_rec(p, sv.y, rv.y, av.y, eidx, esc, vs, SA, SB, g2); }
        unsigned c = (unsigned)(v.z - lo); if (c < 250u) { int p = atomicAdd(&cur[c], 1); fill_rec(p, sv.z, rv.z, av.z, eidx, esc, vs, SA, SB, g2); }
        unsigned d = (unsigned)(v.w - lo); if (d < 250u) { int p = atomicAdd(&cur[d], 1); fill_rec(p, sv.w, rv.w, av.w, eidx, esc, vs, SA, SB, g2); }
    }
}

// ============ STAGE 4: aggregation (1 node/wave) + fused MFMA projection epilogue ============
// score loads now CSR-contiguous via esc (no table gathers on the shuffle chain);
// valh gather is the single remaining dependent round-trip.
__global__ __launch_bounds__(256) void k_agg(
    const __half* __restrict__ valh, const float* __restrict__ vt,
    const float* __restrict__ g1, const float* __restrict__ gate_b,
    const int* __restrict__ rowptr, const int* __restrict__ eidx,
    const float* __restrict__ esc,
    const __half* __restrict__ Wpf, const float* __restrict__ Pb,
    const float* __restrict__ final_bias, float* __restrict__ out)
{
    __shared__ __half lds_cat[4][512];   // 4 KB: cat rows for the block's 4 nodes
    __shared__ float gate_lds[4][8];
    int tid = threadIdx.x, wv = tid >> 6, l = tid & 63;
    int n = blockIdx.x * 4 + wv;
    int beg = rowptr[n], end = rowptr[n + 1];
    int deg = end - beg;
    int h8 = l >> 3, q = l & 7;
    float vtq = vt[(size_t)n * 8 + q];

    float accV = 0.f, accR = 0.f, accG = 0.f;
    float4 av = make_float4(0, 0, 0, 0), ar = make_float4(0, 0, 0, 0);

    for (int base = beg; base < end; base += 64) {
        int cnt = min(64, end - base);
        int rec = 0;
        if (l < cnt) rec = eidx[base + l];
        for (int b0 = 0; b0 < cnt; b0 += 8) {
            int bn = min(8, cnt - b0);
            int se = __shfl(rec, b0 + h8, 64);
            // contiguous score loads (independent of the shuffle chain)
            int ei = base + b0 + ((h8 < bn) ? h8 : (bn - 1));
            const float* ep = esc + (size_t)ei * 24;
            float sVv = ep[q];
            float sRv = ep[8 + q];
            float gvv = ep[16 + q];
            // prefetch the 8 value rows (64 lanes x 8B = full 512B row each)
            uint2 vvb[8];
#pragma unroll
            for (int p = 0; p < 8; ++p) {
                int pp = (p < bn) ? p : (bn - 1);
                int s1 = __shfl(se, pp << 3, 64);   // lane pp*8 holds src of edge pp
                vvb[p] = *(const uint2*)(valh + (size_t)s1 * 256 + l * 4);
            }
            float eV = 0.f, eR = 0.f, gv = 0.f;
            if (h8 < bn) {
                eV = exp2f(leaky(sVv + vtq) * LOG2E);
                eR = exp2f(leaky(sRv + vtq) * LOG2E);
                gv = gvv;
            }
            accV += eV; accR += eR; accG += gv;
#pragma unroll
            for (int p = 0; p < 8; ++p) {
                if (p < bn) {
                    float wV = __shfl(eV, (p << 3) | h8, 64);
                    float wR = __shfl(eR, (p << 3) | h8, 64);
                    float2 f0 = __half22float2(*(__half2*)&vvb[p].x);
                    float2 f1 = __half22float2(*(__half2*)&vvb[p].y);
                    av.x = fmaf(f0.x, wV, av.x); av.y = fmaf(f0.y, wV, av.y);
                    av.z = fmaf(f1.x, wV, av.z); av.w = fmaf(f1.y, wV, av.w);
                    ar.x = fmaf(f0.x, wR, ar.x); ar.y = fmaf(f0.y, wR, ar.y);
                    ar.z = fmaf(f1.x, wR, ar.z); ar.w = fmaf(f1.y, wR, ar.w);
                }
            }
        }
    }
    // butterfly over edge-groups: lanes with equal q sum their per-edge partials
#pragma unroll
    for (int off = 8; off < 64; off <<= 1) {
        accV += __shfl_xor(accV, off, 64);
        accR += __shfl_xor(accR, off, 64);
        accG += __shfl_xor(accG, off, 64);
    }
    // lane h8 (q == h8) holds the full denominator for head h8
    float rdv = 1.f / (__shfl(accV, h8, 64) + EPSV);
    float rdr = 1.f / (__shfl(accR, h8, 64) + EPSV);
    av.x *= rdv; av.y *= rdv; av.z *= rdv; av.w *= rdv;
    ar.x *= rdr; ar.y *= rdr; ar.z *= rdr; ar.w *= rdr;

    // stage cat into LDS: [wv][h*64 + d], V at d 0..31, R at 32..63
    {
        __half* cp = &lds_cat[wv][h8 * 64 + q * 4];
        __half2 a01 = __floats2half2_rn(av.x, av.y);
        __half2 a23 = __floats2half2_rn(av.z, av.w);
        __half2 r01 = __floats2half2_rn(ar.x, ar.y);
        __half2 r23 = __floats2half2_rn(ar.z, ar.w);
        uint2 sa_; sa_.x = *(unsigned*)&a01; sa_.y = *(unsigned*)&a23;
        uint2 sr_; sr_.x = *(unsigned*)&r01; sr_.y = *(unsigned*)&r23;
        *(uint2*)cp = sa_;
        *(uint2*)(cp + 32) = sr_;
    }
    if (l < 8) {   // lane l holds full accG for head l
        float dscale = 1.f / (float)(deg > 1 ? deg : 1);
        float gl = g1[(size_t)n * 8 + l] + accG * dscale + gate_b[l];
        gate_lds[wv][l] = 1.f / (1.f + exp2f(-gl * LOG2E));
    }
    __syncthreads();

    // fused projection: wave wv handles heads {2wv, 2wv+1}; A rows 0..3 real, 4..15 zero
    int n0 = blockIdx.x * 4;
    int l16 = l & 15, hi = l >> 4;
#pragma unroll
    for (int hp = 0; hp < 2; ++hp) {
        int h = wv * 2 + hp;
        f32x4 acc0 = {0.f, 0.f, 0.f, 0.f}, acc1 = {0.f, 0.f, 0.f, 0.f};
#pragma unroll
        for (int kp = 0; kp < 2; ++kp) {
            f16x8 afr = {};
            if (l16 < 4) afr = *(const f16x8*)(&lds_cat[l16][h * 64 + kp * 32 + hi * 8]);
            f16x8 bf0 = *(const f16x8*)(Wpf + (size_t)(((h * 2 + 0) * 2 + kp) * 64 + l) * 8);
            f16x8 bf1 = *(const f16x8*)(Wpf + (size_t)(((h * 2 + 1) * 2 + kp) * 64 + l) * 8);
            acc0 = __builtin_amdgcn_mfma_f32_16x16x32_f16(afr, bf0, acc0, 0, 0, 0);
            acc1 = __builtin_amdgcn_mfma_f32_16x16x32_f16(afr, bf1, acc1, 0, 0, 0);
        }
        if (hi == 0) {   // C rows 0..3 live on quad 0
            float pb0 = Pb[h * 32 + l16],        pb1 = Pb[h * 32 + 16 + l16];
            float fb0 = final_bias[h * 32 + l16], fb1 = final_bias[h * 32 + 16 + l16];
#pragma unroll
            for (int r = 0; r < 4; ++r) {
                int row = n0 + r;
                float g = gate_lds[r][h];
                out[(size_t)row * 256 + h * 32 + l16]      = fmaf(acc0[r] + pb0, g, fb0);
                out[(size_t)row * 256 + h * 32 + 16 + l16] = fmaf(acc1[r] + pb1, g, fb1);
            }
        }
    }
}

extern "C" void kernel_launch(void* const* d_in, const int* in_sizes, int n_in,
                              void* d_out, int out_size, void* d_ws, size_t ws_size,
                              hipStream_t stream) {
    const float* inp         = (const float*)d_in[0];
    const float* W_value     = (const float*)d_in[2];
    const float* W_relation  = (const float*)d_in[3];
    const float* deprel_emb  = (const float*)d_in[4];
    const float* deparc_emb  = (const float*)d_in[5];
    const float* w_src       = (const float*)d_in[6];
    const float* w_tgt       = (const float*)d_in[7];
    const float* w_rel       = (const float*)d_in[8];
    const float* fpw         = (const float*)d_in[9];
    const float* fpb         = (const float*)d_in[10];
    const float* neighbor_w  = (const float*)d_in[11];
    const float* neighbor_b  = (const float*)d_in[12];
    const float* gate_w      = (const float*)d_in[13];
    const float* gate_b      = (const float*)d_in[14];
    const float* final_bias  = (const float*)d_in[15];
    const int*   edge_index  = (const int*)d_in[16];
    const int*   deprel_edge = (const int*)d_in[17];
    const int*   deparc_edge = (const int*)d_in[18];
    const int* srcArr = edge_index;
    const int* tgtArr = edge_index + N_EDGES;
    float* out = (float*)d_out;

    // workspace carve (all offsets 16B-aligned)
    __half* valh = (__half*)d_ws;                                 // 10.24 MB
    unsigned short* Btf = (unsigned short*)(valh + 5120000);      // 160 KB
    float* bg2 = (float*)(Btf + 81920);                           // 8
    float* vs = bg2 + 8;
    float* vt = vs + 160000;
    float* g1 = vt + 160000;
    float* g2 = g1 + 160000;
    float* SA = g2 + 160000;
    float* SB = SA + 400;
    int* cnts = (int*)(SB + 32);                                  // 160,000
    int* rowptr = cnts + 160000;                                  // 20,004 (padded)
    int* eidx = rowptr + 20004;                                   // 160,000 int (src only)
    __half* Wpf = (__half*)(eidx + 160000);                       // 32 KB
    int* rss = (int*)(Wpf + 16384);                               // 640 (range,slice) sums
    float* esc = (float*)(rss + 640);                             // 160,000 x 24 f32 (15.36 MB)

    k_pre<<<914, 256, 0, stream>>>(W_value, neighbor_w, neighbor_b,
                                   w_src, w_tgt, gate_w, Btf, bg2,
                                   W_relation, w_rel, deprel_emb, deparc_emb, SA, SB,
                                   tgtArr, cnts, fpw, Wpf, rss);
    k_mid<<<1330, 256, 0, stream>>>(inp, Btf, bg2, valh, vs, vt, g1, g2, cnts, rss, rowptr);
    k_fill<<<640, 256, 0, stream>>>(srcArr, tgtArr, deprel_edge, deparc_edge,
                                    rowptr, cnts, vs, SA, SB, g2, eidx, esc);
    k_agg<<<N_NODES / 4, 256, 0, stream>>>(valh, vt, g1, gate_b,
                                           rowptr, eidx, esc, Wpf, fpb, final_bias, out);
}

// Round 9
// 172.365 us; speedup vs baseline: 1.3506x; 1.3506x over previous
//
#include <hip/hip_runtime.h>
#include <hip/hip_fp16.h>
#include <math.h>

#define N_NODES 20000
#define N_EDGES 160000
#define EPSV 1e-12f
#define SLOPE 0.2f
#define LOG2E 1.4426950408889634f

__device__ __forceinline__ float leaky(float x) { return x >= 0.f ? x : SLOPE * x; }

__device__ __forceinline__ unsigned short cvt_bf16(float f) {
    unsigned u = __float_as_uint(f);
    u = (u + 0x7FFFu + ((u >> 16) & 1u)) >> 16;
    return (unsigned short)u;
}
__device__ __forceinline__ unsigned pk2(float a, float b) {
    return (unsigned)cvt_bf16(a) | ((unsigned)cvt_bf16(b) << 16);
}

// fragment-ordered Bt index: column n (0..319), k (0..255)
__device__ __forceinline__ int btf_idx(int n, int k) {
    int w = n / 80, rem = n - w * 80, t = rem >> 4, l16 = rem & 15;
    int kk = k >> 5, c = k & 31, quad = c >> 3, e = c & 7;
    int lane = quad * 16 + l16;
    return (((w * 5 + t) * 8 + kk) * 64 + lane) * 8 + e;
}

typedef __attribute__((ext_vector_type(8))) short bf16x8;
typedef __attribute__((ext_vector_type(8))) _Float16 f16x8;
typedef __attribute__((ext_vector_type(4))) float f32x4;

// ============ STAGE 1: fold (0..271) + rel (272) + count (273..912) + Wp pack (913) ============
__global__ __launch_bounds__(256) void k_pre(
    const float* __restrict__ Wv, const float* __restrict__ Wn,
    const float* __restrict__ nbb, const float* __restrict__ wsrc,
    const float* __restrict__ wtgt, const float* __restrict__ gw,
    unsigned short* __restrict__ Btf, float* __restrict__ bg2,
    const float* __restrict__ Wrel, const float* __restrict__ wrel,
    const float* __restrict__ deprel_emb, const float* __restrict__ deparc_emb,
    float* __restrict__ SA, float* __restrict__ SB,
    const int* __restrict__ tgt, int* __restrict__ cnts,
    const float* __restrict__ fpw, __half* __restrict__ Wpf,
    int* __restrict__ rss)
{
    __shared__ float wr2[128 * 8];
    __shared__ int cnt[250];
    __shared__ float gwc[256];
    __shared__ int wtot[4];
    int k = threadIdx.x;
    int b = blockIdx.x;
    if (b < 256) {
        Btf[btf_idx(b, k)] = cvt_bf16(Wv[k * 256 + b]);
    } else if (b < 264) {
        int h = b - 256;
        // stage gw column h (rows 256..511) once: kills 256 stride-8 gathers/thread
        gwc[k] = gw[(256 + k) * 8 + h];
        __syncthreads();
        float a_vs = 0.f, a_vt = 0.f, a_ng = 0.f;
        for (int d = 0; d < 32; ++d) {
            float w = Wv[k * 256 + h * 32 + d];
            a_vs = fmaf(w, wsrc[h * 32 + d], a_vs);
            a_vt = fmaf(w, wtgt[h * 32 + d], a_vt);
        }
        const float4* wn4 = (const float4*)(Wn + (size_t)k * 256);
#pragma unroll 4
        for (int j = 0; j < 64; ++j) {
            float4 w4 = wn4[j];
            a_ng = fmaf(w4.x, gwc[j * 4 + 0], a_ng);
            a_ng = fmaf(w4.y, gwc[j * 4 + 1], a_ng);
            a_ng = fmaf(w4.z, gwc[j * 4 + 2], a_ng);
            a_ng = fmaf(w4.w, gwc[j * 4 + 3], a_ng);
        }
        Btf[btf_idx(256 + h, k)] = cvt_bf16(a_vs);
        Btf[btf_idx(264 + h, k)] = cvt_bf16(a_vt);
        Btf[btf_idx(272 + h, k)] = cvt_bf16(gw[k * 8 + h]);
        Btf[btf_idx(280 + h, k)] = cvt_bf16(a_ng);
        // bg2[h] = nbb . gwc, block-parallel reduce (reuse wr2 as scratch)
        wr2[k] = nbb[k] * gwc[k];
        __syncthreads();
        if (k < 64) {
            float t = wr2[k] + wr2[k + 64] + wr2[k + 128] + wr2[k + 192];
#pragma unroll
            for (int off = 32; off; off >>= 1) t += __shfl_down(t, off, 64);
            if (k == 0) bg2[h] = t;
        }
    } else if (b < 272) {
        int n0 = 288 + (b - 264) * 4;
        for (int i = 0; i < 4; ++i) Btf[btf_idx(n0 + i, k)] = 0;
    } else if (b == 272) {
        for (int i = k; i < 1024; i += 256) {
            int kk = i >> 3, h = i & 7;
            float acc = 0.f;
            for (int r = 0; r < 16; ++r)
                acc += Wrel[kk * 128 + h * 16 + r] * wrel[h * 16 + r];
            wr2[kk * 8 + h] = acc;
        }
        __syncthreads();
        for (int i = k; i < 50 * 8; i += 256) {
            int d = i >> 3, h = i & 7;
            float acc = 0.f;
            for (int kk = 0; kk < 64; ++kk) acc += deprel_emb[d * 64 + kk] * wr2[kk * 8 + h];
            SA[i] = acc;
        }
        for (int i = k; i < 4 * 8; i += 256) {
            int d = i >> 3, h = i & 7;
            float acc = 0.f;
            for (int kk = 0; kk < 64; ++kk) acc += deparc_emb[d * 64 + kk] * wr2[(64 + kk) * 8 + h];
            SB[i] = acc;
        }
    } else if (b < 913) {
        int idx = b - 273;
        int slice = idx & 7, range = idx >> 3;
        int lo = range * 250;
        if (k < 250) cnt[k] = 0;
        __syncthreads();
        const int4* t4 = (const int4*)tgt;
        int i0 = slice * 5000;
        int mc = 0;   // per-thread match count -> block total -> rss[(range,slice)]
#pragma unroll 4
        for (int i = k; i < 5000; i += 256) {
            int4 v = t4[i0 + i];
            unsigned a = (unsigned)(v.x - lo); if (a < 250u) { atomicAdd(&cnt[a], 1); ++mc; }
            unsigned bb = (unsigned)(v.y - lo); if (bb < 250u) { atomicAdd(&cnt[bb], 1); ++mc; }
            unsigned c = (unsigned)(v.z - lo); if (c < 250u) { atomicAdd(&cnt[c], 1); ++mc; }
            unsigned d = (unsigned)(v.w - lo); if (d < 250u) { atomicAdd(&cnt[d], 1); ++mc; }
        }
        __syncthreads();
        if (k < 250) cnts[(lo + k) * 8 + slice] = cnt[k];
#pragma unroll
        for (int off = 32; off; off >>= 1) mc += __shfl_down(mc, off, 64);
        if ((k & 63) == 0) wtot[k >> 6] = mc;
        __syncthreads();
        if (k == 0) rss[idx] = wtot[0] + wtot[1] + wtot[2] + wtot[3];
    } else {
        // pack final_proj_w into f16 MFMA B-fragments:
        // Wpf[((h*2+jt)*2+kp)*64 + lane][e] = Wp[h][kp*32 + (lane>>4)*8 + e][jt*16 + (lane&15)]
        for (int i = k; i < 2048; i += 256) {
            int lane = i & 63, kp = (i >> 6) & 1, jt = (i >> 7) & 1, h = i >> 8;
            int col = jt * 16 + (lane & 15);
            int krow = kp * 32 + (lane >> 4) * 8;
#pragma unroll
            for (int e = 0; e < 8; ++e)
                Wpf[(size_t)i * 8 + e] = __float2half(fpw[h * 2048 + (krow + e) * 32 + col]);
        }
    }
}

// ============ STAGE 2: mfma (0..1249) + parallel range scans (1250..1329) ============
// scan also writes cur[] (working copy of rowptr for the atomic fill)
__global__ __launch_bounds__(256) void k_mid(
    const float* __restrict__ inp, const unsigned short* __restrict__ Btf,
    const float* __restrict__ bg2, __half* __restrict__ valh,
    float* __restrict__ vs, float* __restrict__ vt,
    float* __restrict__ g1, float* __restrict__ g2,
    const int* __restrict__ cnts, const int* __restrict__ rss,
    int* __restrict__ rowptr, int* __restrict__ cur)
{
    __shared__ int red[4], red2[4];
    int tid = threadIdx.x;
    if (blockIdx.x < 1250) {
        int wave = tid >> 6, lane = tid & 63;
        int quad = lane >> 4, l16 = lane & 15;
        int row0 = blockIdx.x * 16;
        const float* arow = inp + (size_t)(row0 + l16) * 256;
        bf16x8 afr[8];
#pragma unroll
        for (int kk = 0; kk < 8; ++kk) {
            float4 f0 = *(const float4*)(arow + kk * 32 + quad * 8);
            float4 f1 = *(const float4*)(arow + kk * 32 + quad * 8 + 4);
            union { unsigned u[4]; bf16x8 v; } cv;
            cv.u[0] = pk2(f0.x, f0.y); cv.u[1] = pk2(f0.z, f0.w);
            cv.u[2] = pk2(f1.x, f1.y); cv.u[3] = pk2(f1.z, f1.w);
            afr[kk] = cv.v;
        }
        f32x4 acc[5] = {};
#pragma unroll
        for (int kk = 0; kk < 8; ++kk) {
#pragma unroll
            for (int t = 0; t < 5; ++t) {
                bf16x8 bf = *(const bf16x8*)(Btf + (((wave * 5 + t) * 8 + kk) * 64 + lane) * 8);
                acc[t] = __builtin_amdgcn_mfma_f32_16x16x32_bf16(afr[kk], bf, acc[t], 0, 0, 0);
            }
        }
#pragma unroll
        for (int t = 0; t < 5; ++t) {
            int n = wave * 80 + t * 16 + l16;
#pragma unroll
            for (int r = 0; r < 4; ++r) {
                int row = row0 + quad * 4 + r;
                float v = acc[t][r];
                if (n < 256) {
                    valh[(size_t)row * 256 + n] = __float2half(v);
                } else if (n < 288) {
                    int c2 = n - 256, which = c2 >> 3, h = c2 & 7;
                    if (which == 3) v += bg2[h];
                    float* dst = (which == 0) ? vs : (which == 1) ? vt : (which == 2) ? g1 : g2;
                    dst[(size_t)row * 8 + h] = v;
                }
            }
        }
    } else {
        int r = blockIdx.x - 1250;       // range 0..79
        int lo = r * 250;
        int lane = tid & 63, w = tid >> 6;
        // base = number of edges landing in ranges < r
        int m = r * 8;
        int part = 0;
        for (int i = tid; i < m; i += 256) part += rss[i];
#pragma unroll
        for (int off = 32; off; off >>= 1) part += __shfl_down(part, off, 64);
        if (lane == 0) red[w] = part;
        // local degree of node lo+tid
        int deg = 0;
        if (tid < 250) {
            const int4* c4 = (const int4*)(cnts + (size_t)(lo + tid) * 8);
            int4 a = c4[0], b2 = c4[1];
            deg = a.x + a.y + a.z + a.w + b2.x + b2.y + b2.z + b2.w;
        }
        int ps = deg;
#pragma unroll
        for (int off = 1; off < 64; off <<= 1) {
            int x = __shfl_up(ps, off, 64);
            if (lane >= off) ps += x;
        }
        if (lane == 63) red2[w] = ps;
        __syncthreads();
        int base = red[0] + red[1] + red[2] + red[3];
        int wo = 0;
        for (int i = 0; i < w; ++i) wo += red2[i];
        if (tid < 250) {
            int rp = base + wo + ps - deg;
            rowptr[lo + tid] = rp;
            cur[lo + tid] = rp;
        }
        if (r == 79 && tid == 0) rowptr[N_NODES] = N_EDGES;
    }
}

// ============ STAGE 3: single-pass fill via global atomics (each edge read once) ============
__global__ __launch_bounds__(256) void k_fill(
    const int* __restrict__ src, const int* __restrict__ tgt,
    const int* __restrict__ deprel, const int* __restrict__ deparc,
    int* __restrict__ cur, int4* __restrict__ eidx4)
{
    int i = blockIdx.x * 256 + threadIdx.x;
    if (i >= N_EDGES / 4) return;
    const int4* t4 = (const int4*)tgt;
    const int4* s4 = (const int4*)src;
    const int4* r4 = (const int4*)deprel;
    const int4* a4 = (const int4*)deparc;
    int4 v = t4[i];
    int4 sv = s4[i];
    int4 rv = r4[i];
    int4 av = a4[i];
    int p0 = atomicAdd(&cur[v.x], 1); eidx4[p0] = make_int4(sv.x, rv.x, av.x, 0);
    int p1 = atomicAdd(&cur[v.y], 1); eidx4[p1] = make_int4(sv.y, rv.y, av.y, 0);
    int p2 = atomicAdd(&cur[v.z], 1); eidx4[p2] = make_int4(sv.z, rv.z, av.z, 0);
    int p3 = atomicAdd(&cur[v.w], 1); eidx4[p3] = make_int4(sv.w, rv.w, av.w, 0);
}

// ============ STAGE 4: aggregation (1 node/wave) + fused MFMA projection epilogue ============
// edge phase: lane l score role = (edge l>>3, head l&7); accumulate role = (head l>>3, dims (l&7)*4)
__global__ __launch_bounds__(256) void k_agg(
    const __half* __restrict__ valh, const float* __restrict__ vs,
    const float* __restrict__ vt, const float* __restrict__ SA,
    const float* __restrict__ SB, const float* __restrict__ g2,
    const float* __restrict__ g1, const float* __restrict__ gate_b,
    const int* __restrict__ rowptr, const int4* __restrict__ eidx4,
    const __half* __restrict__ Wpf, const float* __restrict__ Pb,
    const float* __restrict__ final_bias, float* __restrict__ out)
{
    __shared__ __half lds_cat[4][512];   // 4 KB: cat rows for the block's 4 nodes
    __shared__ float gate_lds[4][8];
    int tid = threadIdx.x, wv = tid >> 6, l = tid & 63;
    int n = blockIdx.x * 4 + wv;
    int beg = rowptr[n], end = rowptr[n + 1];
    int deg = end - beg;
    int h8 = l >> 3, q = l & 7;
    float vtq = vt[(size_t)n * 8 + q];

    float accV = 0.f, accR = 0.f, accG = 0.f;
    float4 av = make_float4(0, 0, 0, 0), ar = make_float4(0, 0, 0, 0);

    for (int base = beg; base < end; base += 64) {
        int cnt = min(64, end - base);
        int4 rec = make_int4(0, 0, 0, 0);
        if (l < cnt) rec = eidx4[base + l];
        for (int b0 = 0; b0 < cnt; b0 += 8) {
            int bn = min(8, cnt - b0);
            // per-lane edge/head mapping (edge h8, head q)
            int se = __shfl(rec.x, b0 + h8, 64);
            int dr = __shfl(rec.y, b0 + h8, 64);
            int da = __shfl(rec.z, b0 + h8, 64);
            // prefetch the 8 value rows (64 lanes x 8B = full 512B row each)
            uint2 vvb[8];
#pragma unroll
            for (int p = 0; p < 8; ++p) {
                int pp = (p < bn) ? p : (bn - 1);
                int s1 = __shfl(se, pp << 3, 64);   // lane pp*8 holds src of edge pp
                vvb[p] = *(const uint2*)(valh + (size_t)s1 * 256 + l * 4);
            }
            // lane-parallel exp scores (hoisted out of the accumulate chain)
            float eV = 0.f, eR = 0.f, gv = 0.f;
            if (h8 < bn) {
                float sa = vs[(size_t)se * 8 + q] + vtq;
                float sr = SA[dr * 8 + q] + SB[da * 8 + q] + vtq;
                eV = exp2f(leaky(sa) * LOG2E);
                eR = exp2f(leaky(sr) * LOG2E);
                gv = g2[(size_t)se * 8 + q];
            }
            accV += eV; accR += eR; accG += gv;
#pragma unroll
            for (int p = 0; p < 8; ++p) {
                if (p < bn) {
                    float wV = __shfl(eV, (p << 3) | h8, 64);
                    float wR = __shfl(eR, (p << 3) | h8, 64);
                    float2 f0 = __half22float2(*(__half2*)&vvb[p].x);
                    float2 f1 = __half22float2(*(__half2*)&vvb[p].y);
                    av.x = fmaf(f0.x, wV, av.x); av.y = fmaf(f0.y, wV, av.y);
                    av.z = fmaf(f1.x, wV, av.z); av.w = fmaf(f1.y, wV, av.w);
                    ar.x = fmaf(f0.x, wR, ar.x); ar.y = fmaf(f0.y, wR, ar.y);
                    ar.z = fmaf(f1.x, wR, ar.z); ar.w = fmaf(f1.y, wR, ar.w);
                }
            }
        }
    }
    // butterfly over edge-groups: lanes with equal q sum their per-edge partials
#pragma unroll
    for (int off = 8; off < 64; off <<= 1) {
        accV += __shfl_xor(accV, off, 64);
        accR += __shfl_xor(accR, off, 64);
        accG += __shfl_xor(accG, off, 64);
    }
    // lane h8 (q == h8) holds the full denominator for head h8
    float rdv = 1.f / (__shfl(accV, h8, 64) + EPSV);
    float rdr = 1.f / (__shfl(accR, h8, 64) + EPSV);
    av.x *= rdv; av.y *= rdv; av.z *= rdv; av.w *= rdv;
    ar.x *= rdr; ar.y *= rdr; ar.z *= rdr; ar.w *= rdr;

    // stage cat into LDS: [wv][h*64 + d], V at d 0..31, R at 32..63
    {
        __half* cp = &lds_cat[wv][h8 * 64 + q * 4];
        __half2 a01 = __floats2half2_rn(av.x, av.y);
        __half2 a23 = __floats2half2_rn(av.z, av.w);
        __half2 r01 = __floats2half2_rn(ar.x, ar.y);
        __half2 r23 = __floats2half2_rn(ar.z, ar.w);
        uint2 sa_; sa_.x = *(unsigned*)&a01; sa_.y = *(unsigned*)&a23;
        uint2 sr_; sr_.x = *(unsigned*)&r01; sr_.y = *(unsigned*)&r23;
        *(uint2*)cp = sa_;
        *(uint2*)(cp + 32) = sr_;
    }
    if (l < 8) {   // lane l holds full accG for head l
        float dscale = 1.f / (float)(deg > 1 ? deg : 1);
        float gl = g1[(size_t)n * 8 + l] + accG * dscale + gate_b[l];
        gate_lds[wv][l] = 1.f / (1.f + exp2f(-gl * LOG2E));
    }
    __syncthreads();

    // fused projection: wave wv handles heads {2wv, 2wv+1}; A rows 0..3 real, 4..15 zero
    int n0 = blockIdx.x * 4;
    int l16 = l & 15, hi = l >> 4;
#pragma unroll
    for (int hp = 0; hp < 2; ++hp) {
        int h = wv * 2 + hp;
        f32x4 acc0 = {0.f, 0.f, 0.f, 0.f}, acc1 = {0.f, 0.f, 0.f, 0.f};
#pragma unroll
        for (int kp = 0; kp < 2; ++kp) {
            f16x8 afr = {};
            if (l16 < 4) afr = *(const f16x8*)(&lds_cat[l16][h * 64 + kp * 32 + hi * 8]);
            f16x8 bf0 = *(const f16x8*)(Wpf + (size_t)(((h * 2 + 0) * 2 + kp) * 64 + l) * 8);
            f16x8 bf1 = *(const f16x8*)(Wpf + (size_t)(((h * 2 + 1) * 2 + kp) * 64 + l) * 8);
            acc0 = __builtin_amdgcn_mfma_f32_16x16x32_f16(afr, bf0, acc0, 0, 0, 0);
            acc1 = __builtin_amdgcn_mfma_f32_16x16x32_f16(afr, bf1, acc1, 0, 0, 0);
        }
        if (hi == 0) {   // C rows 0..3 live on quad 0
            float pb0 = Pb[h * 32 + l16],        pb1 = Pb[h * 32 + 16 + l16];
            float fb0 = final_bias[h * 32 + l16], fb1 = final_bias[h * 32 + 16 + l16];
#pragma unroll
            for (int r = 0; r < 4; ++r) {
                int row = n0 + r;
                float g = gate_lds[r][h];
                out[(size_t)row * 256 + h * 32 + l16]      = fmaf(acc0[r] + pb0, g, fb0);
                out[(size_t)row * 256 + h * 32 + 16 + l16] = fmaf(acc1[r] + pb1, g, fb1);
            }
        }
    }
}

extern "C" void kernel_launch(void* const* d_in, const int* in_sizes, int n_in,
                              void* d_out, int out_size, void* d_ws, size_t ws_size,
                              hipStream_t stream) {
    const float* inp         = (const float*)d_in[0];
    const float* W_value     = (const float*)d_in[2];
    const float* W_relation  = (const float*)d_in[3];
    const float* deprel_emb  = (const float*)d_in[4];
    const float* deparc_emb  = (const float*)d_in[5];
    const float* w_src       = (const float*)d_in[6];
    const float* w_tgt       = (const float*)d_in[7];
    const float* w_rel       = (const float*)d_in[8];
    const float* fpw         = (const float*)d_in[9];
    const float* fpb         = (const float*)d_in[10];
    const float* neighbor_w  = (const float*)d_in[11];
    const float* neighbor_b  = (const float*)d_in[12];
    const float* gate_w      = (const float*)d_in[13];
    const float* gate_b      = (const float*)d_in[14];
    const float* final_bias  = (const float*)d_in[15];
    const int*   edge_index  = (const int*)d_in[16];
    const int*   deprel_edge = (const int*)d_in[17];
    const int*   deparc_edge = (const int*)d_in[18];
    const int* srcArr = edge_index;
    const int* tgtArr = edge_index + N_EDGES;
    float* out = (float*)d_out;

    // workspace carve (all offsets 16B-aligned)
    __half* valh = (__half*)d_ws;                                 // 10.24 MB
    unsigned short* Btf = (unsigned short*)(valh + 5120000);      // 160 KB
    float* bg2 = (float*)(Btf + 81920);                           // 8
    float* vs = bg2 + 8;
    float* vt = vs + 160000;
    float* g1 = vt + 160000;
    float* g2 = g1 + 160000;
    float* SA = g2 + 160000;
    float* SB = SA + 400;
    int* cnts = (int*)(SB + 32);                                  // 160,000
    int* rowptr = cnts + 160000;                                  // 20,004 (padded)
    int4* eidx4 = (int4*)(rowptr + 20004);                        // 160,000 int4
    __half* Wpf = (__half*)(eidx4 + 160000);                      // 32 KB
    int* rss = (int*)(Wpf + 16384);                               // 640 (range,slice) sums
    int* cur = rss + 640;                                         // 20,000 working rowptr copy

    k_pre<<<914, 256, 0, stream>>>(W_value, neighbor_w, neighbor_b,
                                   w_src, w_tgt, gate_w, Btf, bg2,
                                   W_relation, w_rel, deprel_emb, deparc_emb, SA, SB,
                                   tgtArr, cnts, fpw, Wpf, rss);
    k_mid<<<1330, 256, 0, stream>>>(inp, Btf, bg2, valh, vs, vt, g1, g2, cnts, rss,
                                    rowptr, cur);
    k_fill<<<(N_EDGES / 4 + 255) / 256, 256, 0, stream>>>(srcArr, tgtArr, deprel_edge,
                                                          deparc_edge, cur, eidx4);
    k_agg<<<N_NODES / 4, 256, 0, stream>>>(valh, vs, vt, SA, SB, g2, g1, gate_b,
                                           rowptr, eidx4, Wpf, fpb, final_bias, out);
}

// Round 10
// 171.560 us; speedup vs baseline: 1.3570x; 1.0047x over previous
//
#include <hip/hip_runtime.h>
#include <hip/hip_fp16.h>
#include <math.h>

#define N_NODES 20000
#define N_EDGES 160000
#define EPSV 1e-12f
#define SLOPE 0.2f
#define LOG2E 1.4426950408889634f

__device__ __forceinline__ float leaky(float x) { return x >= 0.f ? x : SLOPE * x; }

__device__ __forceinline__ unsigned short cvt_bf16(float f) {
    unsigned u = __float_as_uint(f);
    u = (u + 0x7FFFu + ((u >> 16) & 1u)) >> 16;
    return (unsigned short)u;
}
__device__ __forceinline__ unsigned pk2(float a, float b) {
    return (unsigned)cvt_bf16(a) | ((unsigned)cvt_bf16(b) << 16);
}

// fragment-ordered Bt index: column n (0..319), k (0..255)
__device__ __forceinline__ int btf_idx(int n, int k) {
    int w = n / 80, rem = n - w * 80, t = rem >> 4, l16 = rem & 15;
    int kk = k >> 5, c = k & 31, quad = c >> 3, e = c & 7;
    int lane = quad * 16 + l16;
    return (((w * 5 + t) * 8 + kk) * 64 + lane) * 8 + e;
}

typedef __attribute__((ext_vector_type(8))) short bf16x8;
typedef __attribute__((ext_vector_type(8))) _Float16 f16x8;
typedef __attribute__((ext_vector_type(4))) float f32x4;

// ============ STAGE 1: fold (0..271) + rel/SAB (272) + count (273..912) + Wp pack (913) ============
__global__ __launch_bounds__(256) void k_pre(
    const float* __restrict__ Wv, const float* __restrict__ Wn,
    const float* __restrict__ nbb, const float* __restrict__ wsrc,
    const float* __restrict__ wtgt, const float* __restrict__ gw,
    unsigned short* __restrict__ Btf, float* __restrict__ bg2,
    const float* __restrict__ Wrel, const float* __restrict__ wrel,
    const float* __restrict__ deprel_emb, const float* __restrict__ deparc_emb,
    float* __restrict__ SA, float* __restrict__ SB, float* __restrict__ SAB,
    const int* __restrict__ tgt, int* __restrict__ cnts,
    const float* __restrict__ fpw, __half* __restrict__ Wpf,
    int* __restrict__ rss)
{
    __shared__ float wr2[128 * 8];
    __shared__ int cnt[250];
    __shared__ float gwc[256];
    __shared__ int wtot[4];
    int k = threadIdx.x;
    int b = blockIdx.x;
    if (b < 256) {
        Btf[btf_idx(b, k)] = cvt_bf16(Wv[k * 256 + b]);
    } else if (b < 264) {
        int h = b - 256;
        // stage gw column h (rows 256..511) once: kills 256 stride-8 gathers/thread
        gwc[k] = gw[(256 + k) * 8 + h];
        __syncthreads();
        float a_vs = 0.f, a_vt = 0.f, a_ng = 0.f;
        for (int d = 0; d < 32; ++d) {
            float w = Wv[k * 256 + h * 32 + d];
            a_vs = fmaf(w, wsrc[h * 32 + d], a_vs);
            a_vt = fmaf(w, wtgt[h * 32 + d], a_vt);
        }
        const float4* wn4 = (const float4*)(Wn + (size_t)k * 256);
#pragma unroll 4
        for (int j = 0; j < 64; ++j) {
            float4 w4 = wn4[j];
            a_ng = fmaf(w4.x, gwc[j * 4 + 0], a_ng);
            a_ng = fmaf(w4.y, gwc[j * 4 + 1], a_ng);
            a_ng = fmaf(w4.z, gwc[j * 4 + 2], a_ng);
            a_ng = fmaf(w4.w, gwc[j * 4 + 3], a_ng);
        }
        Btf[btf_idx(256 + h, k)] = cvt_bf16(a_vs);
        Btf[btf_idx(264 + h, k)] = cvt_bf16(a_vt);
        Btf[btf_idx(272 + h, k)] = cvt_bf16(gw[k * 8 + h]);
        Btf[btf_idx(280 + h, k)] = cvt_bf16(a_ng);
        // bg2[h] = nbb . gwc, block-parallel reduce (reuse wr2 as scratch)
        wr2[k] = nbb[k] * gwc[k];
        __syncthreads();
        if (k < 64) {
            float t = wr2[k] + wr2[k + 64] + wr2[k + 128] + wr2[k + 192];
#pragma unroll
            for (int off = 32; off; off >>= 1) t += __shfl_down(t, off, 64);
            if (k == 0) bg2[h] = t;
        }
    } else if (b < 272) {
        int n0 = 288 + (b - 264) * 4;
        for (int i = 0; i < 4; ++i) Btf[btf_idx(n0 + i, k)] = 0;
    } else if (b == 272) {
        for (int i = k; i < 1024; i += 256) {
            int kk = i >> 3, h = i & 7;
            float acc = 0.f;
            for (int r = 0; r < 16; ++r)
                acc += Wrel[kk * 128 + h * 16 + r] * wrel[h * 16 + r];
            wr2[kk * 8 + h] = acc;
        }
        __syncthreads();
        for (int i = k; i < 50 * 8; i += 256) {
            int d = i >> 3, h = i & 7;
            float acc = 0.f;
            for (int kk = 0; kk < 64; ++kk) acc += deprel_emb[d * 64 + kk] * wr2[kk * 8 + h];
            SA[i] = acc;
        }
        for (int i = k; i < 4 * 8; i += 256) {
            int d = i >> 3, h = i & 7;
            float acc = 0.f;
            for (int kk = 0; kk < 64; ++kk) acc += deparc_emb[d * 64 + kk] * wr2[(64 + kk) * 8 + h];
            SB[i] = acc;
        }
        __syncthreads();   // SA/SB stores drained before re-read (same block, same L2)
        // combined relation table: SAB[(dr*4+da)*8+q] = SA[dr*8+q] + SB[da*8+q]
        for (int i = k; i < 1600; i += 256) {
            int q = i & 7, rel = i >> 3, da = rel & 3, dr = rel >> 2;
            SAB[i] = SA[dr * 8 + q] + SB[da * 8 + q];
        }
    } else if (b < 913) {
        int idx = b - 273;
        int slice = idx & 7, range = idx >> 3;
        int lo = range * 250;
        if (k < 250) cnt[k] = 0;
        __syncthreads();
        const int4* t4 = (const int4*)tgt;
        int i0 = slice * 5000;
        int mc = 0;   // per-thread match count -> block total -> rss[(range,slice)]
#pragma unroll 4
        for (int i = k; i < 5000; i += 256) {
            int4 v = t4[i0 + i];
            unsigned a = (unsigned)(v.x - lo); if (a < 250u) { atomicAdd(&cnt[a], 1); ++mc; }
            unsigned bb = (unsigned)(v.y - lo); if (bb < 250u) { atomicAdd(&cnt[bb], 1); ++mc; }
            unsigned c = (unsigned)(v.z - lo); if (c < 250u) { atomicAdd(&cnt[c], 1); ++mc; }
            unsigned d = (unsigned)(v.w - lo); if (d < 250u) { atomicAdd(&cnt[d], 1); ++mc; }
        }
        __syncthreads();
        if (k < 250) cnts[(lo + k) * 8 + slice] = cnt[k];
#pragma unroll
        for (int off = 32; off; off >>= 1) mc += __shfl_down(mc, off, 64);
        if ((k & 63) == 0) wtot[k >> 6] = mc;
        __syncthreads();
        if (k == 0) rss[idx] = wtot[0] + wtot[1] + wtot[2] + wtot[3];
    } else {
        // pack final_proj_w into f16 MFMA B-fragments:
        // Wpf[((h*2+jt)*2+kp)*64 + lane][e] = Wp[h][kp*32 + (lane>>4)*8 + e][jt*16 + (lane&15)]
        for (int i = k; i < 2048; i += 256) {
            int lane = i & 63, kp = (i >> 6) & 1, jt = (i >> 7) & 1, h = i >> 8;
            int col = jt * 16 + (lane & 15);
            int krow = kp * 32 + (lane >> 4) * 8;
#pragma unroll
            for (int e = 0; e < 8; ++e)
                Wpf[(size_t)i * 8 + e] = __float2half(fpw[h * 2048 + (krow + e) * 32 + col]);
        }
    }
}

// ============ STAGE 2: mfma (0..1249) + parallel range scans (1250..1329) ============
// scan also writes cur[] (working copy of rowptr for the atomic fill)
__global__ __launch_bounds__(256) void k_mid(
    const float* __restrict__ inp, const unsigned short* __restrict__ Btf,
    const float* __restrict__ bg2, __half* __restrict__ valh,
    float* __restrict__ vs, float* __restrict__ vt,
    float* __restrict__ g1, float* __restrict__ g2,
    const int* __restrict__ cnts, const int* __restrict__ rss,
    int* __restrict__ rowptr, int* __restrict__ cur)
{
    __shared__ int red[4], red2[4];
    int tid = threadIdx.x;
    if (blockIdx.x < 1250) {
        int wave = tid >> 6, lane = tid & 63;
        int quad = lane >> 4, l16 = lane & 15;
        int row0 = blockIdx.x * 16;
        const float* arow = inp + (size_t)(row0 + l16) * 256;
        bf16x8 afr[8];
#pragma unroll
        for (int kk = 0; kk < 8; ++kk) {
            float4 f0 = *(const float4*)(arow + kk * 32 + quad * 8);
            float4 f1 = *(const float4*)(arow + kk * 32 + quad * 8 + 4);
            union { unsigned u[4]; bf16x8 v; } cv;
            cv.u[0] = pk2(f0.x, f0.y); cv.u[1] = pk2(f0.z, f0.w);
            cv.u[2] = pk2(f1.x, f1.y); cv.u[3] = pk2(f1.z, f1.w);
            afr[kk] = cv.v;
        }
        f32x4 acc[5] = {};
#pragma unroll
        for (int kk = 0; kk < 8; ++kk) {
#pragma unroll
            for (int t = 0; t < 5; ++t) {
                bf16x8 bf = *(const bf16x8*)(Btf + (((wave * 5 + t) * 8 + kk) * 64 + lane) * 8);
                acc[t] = __builtin_amdgcn_mfma_f32_16x16x32_bf16(afr[kk], bf, acc[t], 0, 0, 0);
            }
        }
#pragma unroll
        for (int t = 0; t < 5; ++t) {
            int n = wave * 80 + t * 16 + l16;
#pragma unroll
            for (int r = 0; r < 4; ++r) {
                int row = row0 + quad * 4 + r;
                float v = acc[t][r];
                if (n < 256) {
                    valh[(size_t)row * 256 + n] = __float2half(v);
                } else if (n < 288) {
                    int c2 = n - 256, which = c2 >> 3, h = c2 & 7;
                    if (which == 3) v += bg2[h];
                    float* dst = (which == 0) ? vs : (which == 1) ? vt : (which == 2) ? g1 : g2;
                    dst[(size_t)row * 8 + h] = v;
                }
            }
        }
    } else {
        int r = blockIdx.x - 1250;       // range 0..79
        int lo = r * 250;
        int lane = tid & 63, w = tid >> 6;
        // base = number of edges landing in ranges < r
        int m = r * 8;
        int part = 0;
        for (int i = tid; i < m; i += 256) part += rss[i];
#pragma unroll
        for (int off = 32; off; off >>= 1) part += __shfl_down(part, off, 64);
        if (lane == 0) red[w] = part;
        // local degree of node lo+tid
        int deg = 0;
        if (tid < 250) {
            const int4* c4 = (const int4*)(cnts + (size_t)(lo + tid) * 8);
            int4 a = c4[0], b2 = c4[1];
            deg = a.x + a.y + a.z + a.w + b2.x + b2.y + b2.z + b2.w;
        }
        int ps = deg;
#pragma unroll
        for (int off = 1; off < 64; off <<= 1) {
            int x = __shfl_up(ps, off, 64);
            if (lane >= off) ps += x;
        }
        if (lane == 63) red2[w] = ps;
        __syncthreads();
        int base = red[0] + red[1] + red[2] + red[3];
        int wo = 0;
        for (int i = 0; i < w; ++i) wo += red2[i];
        if (tid < 250) {
            int rp = base + wo + ps - deg;
            rowptr[lo + tid] = rp;
            cur[lo + tid] = rp;
        }
        if (r == 79 && tid == 0) rowptr[N_NODES] = N_EDGES;
    }
}

// ============ STAGE 3: single-pass fill via global atomics, packed 23-bit records ============
// rec = src | (deprel*4 + deparc) << 15   (src < 2^15, rel < 200)
__global__ __launch_bounds__(256) void k_fill(
    const int* __restrict__ src, const int* __restrict__ tgt,
    const int* __restrict__ deprel, const int* __restrict__ deparc,
    int* __restrict__ cur, int* __restrict__ eidx)
{
    int i = blockIdx.x * 256 + threadIdx.x;
    if (i >= N_EDGES / 4) return;
    const int4* t4 = (const int4*)tgt;
    const int4* s4 = (const int4*)src;
    const int4* r4 = (const int4*)deprel;
    const int4* a4 = (const int4*)deparc;
    int4 v = t4[i];
    int4 sv = s4[i];
    int4 rv = r4[i];
    int4 av = a4[i];
    int p0 = atomicAdd(&cur[v.x], 1); eidx[p0] = sv.x | ((rv.x * 4 + av.x) << 15);
    int p1 = atomicAdd(&cur[v.y], 1); eidx[p1] = sv.y | ((rv.y * 4 + av.y) << 15);
    int p2 = atomicAdd(&cur[v.z], 1); eidx[p2] = sv.z | ((rv.z * 4 + av.z) << 15);
    int p3 = atomicAdd(&cur[v.w], 1); eidx[p3] = sv.w | ((rv.w * 4 + av.w) << 15);
}

// ============ STAGE 4: aggregation (1 node/wave) + fused MFMA projection epilogue ============
// packed rec: 1 shuffle/role (was 3), 1-deep shuffle chain on the valh-prefetch path (was 2),
// SAB combined-relation table: 3 score gathers (was 4).
__global__ __launch_bounds__(256) void k_agg(
    const __half* __restrict__ valh, const float* __restrict__ vs,
    const float* __restrict__ vt, const float* __restrict__ SAB,
    const float* __restrict__ g2, const float* __restrict__ g1,
    const float* __restrict__ gate_b,
    const int* __restrict__ rowptr, const int* __restrict__ eidx,
    const __half* __restrict__ Wpf, const float* __restrict__ Pb,
    const float* __restrict__ final_bias, float* __restrict__ out)
{
    __shared__ __half lds_cat[4][512];   // 4 KB: cat rows for the block's 4 nodes
    __shared__ float gate_lds[4][8];
    int tid = threadIdx.x, wv = tid >> 6, l = tid & 63;
    int n = blockIdx.x * 4 + wv;
    int beg = rowptr[n], end = rowptr[n + 1];
    int deg = end - beg;
    int h8 = l >> 3, q = l & 7;
    float vtq = vt[(size_t)n * 8 + q];

    float accV = 0.f, accR = 0.f, accG = 0.f;
    float4 av = make_float4(0, 0, 0, 0), ar = make_float4(0, 0, 0, 0);

    for (int base = beg; base < end; base += 64) {
        int cnt = min(64, end - base);
        int rec = 0;    // packed: se=0, rel=0 for inactive lanes -> safe gathers
        if (l < cnt) rec = eidx[base + l];
        for (int b0 = 0; b0 < cnt; b0 += 8) {
            int bn = min(8, cnt - b0);
            // value prefetch: single-shuffle chain direct from rec
            uint2 vvb[8];
#pragma unroll
            for (int p = 0; p < 8; ++p) {
                int pp = (p < bn) ? p : (bn - 1);
                int s1 = __shfl(rec, b0 + pp, 64) & 0x7FFF;
                vvb[p] = *(const uint2*)(valh + (size_t)s1 * 256 + l * 4);
            }
            // score role: edge h8, head q (one shuffle, unpack in VALU)
            int w = __shfl(rec, b0 + h8, 64);   // b0+h8 >= cnt -> rec=0 -> safe
            int se = w & 0x7FFF, ri = ((unsigned)w) >> 15;
            float eV = 0.f, eR = 0.f, gv = 0.f;
            if (h8 < bn) {
                float sa = vs[(size_t)se * 8 + q] + vtq;
                float sr = SAB[ri * 8 + q] + vtq;
                eV = exp2f(leaky(sa) * LOG2E);
                eR = exp2f(leaky(sr) * LOG2E);
                gv = g2[(size_t)se * 8 + q];
            }
            accV += eV; accR += eR; accG += gv;
#pragma unroll
            for (int p = 0; p < 8; ++p) {
                if (p < bn) {
                    float wV = __shfl(eV, (p << 3) | h8, 64);
                    float wR = __shfl(eR, (p << 3) | h8, 64);
                    float2 f0 = __half22float2(*(__half2*)&vvb[p].x);
                    float2 f1 = __half22float2(*(__half2*)&vvb[p].y);
                    av.x = fmaf(f0.x, wV, av.x); av.y = fmaf(f0.y, wV, av.y);
                    av.z = fmaf(f1.x, wV, av.z); av.w = fmaf(f1.y, wV, av.w);
                    ar.x = fmaf(f0.x, wR, ar.x); ar.y = fmaf(f0.y, wR, ar.y);
                    ar.z = fmaf(f1.x, wR, ar.z); ar.w = fmaf(f1.y, wR, ar.w);
                }
            }
        }
    }
    // butterfly over edge-groups: lanes with equal q sum their per-edge partials
#pragma unroll
    for (int off = 8; off < 64; off <<= 1) {
        accV += __shfl_xor(accV, off, 64);
        accR += __shfl_xor(accR, off, 64);
        accG += __shfl_xor(accG, off, 64);
    }
    // lane h8 (q == h8) holds the full denominator for head h8
    float rdv = 1.f / (__shfl(accV, h8, 64) + EPSV);
    float rdr = 1.f / (__shfl(accR, h8, 64) + EPSV);
    av.x *= rdv; av.y *= rdv; av.z *= rdv; av.w *= rdv;
    ar.x *= rdr; ar.y *= rdr; ar.z *= rdr; ar.w *= rdr;

    // stage cat into LDS: [wv][h*64 + d], V at d 0..31, R at 32..63
    {
        __half* cp = &lds_cat[wv][h8 * 64 + q * 4];
        __half2 a01 = __floats2half2_rn(av.x, av.y);
        __half2 a23 = __floats2half2_rn(av.z, av.w);
        __half2 r01 = __floats2half2_rn(ar.x, ar.y);
        __half2 r23 = __floats2half2_rn(ar.z, ar.w);
        uint2 sa_; sa_.x = *(unsigned*)&a01; sa_.y = *(unsigned*)&a23;
        uint2 sr_; sr_.x = *(unsigned*)&r01; sr_.y = *(unsigned*)&r23;
        *(uint2*)cp = sa_;
        *(uint2*)(cp + 32) = sr_;
    }
    if (l < 8) {   // lane l holds full accG for head l
        float dscale = 1.f / (float)(deg > 1 ? deg : 1);
        float gl = g1[(size_t)n * 8 + l] + accG * dscale + gate_b[l];
        gate_lds[wv][l] = 1.f / (1.f + exp2f(-gl * LOG2E));
    }
    __syncthreads();

    // fused projection: wave wv handles heads {2wv, 2wv+1}; A rows 0..3 real, 4..15 zero
    int n0 = blockIdx.x * 4;
    int l16 = l & 15, hi = l >> 4;
#pragma unroll
    for (int hp = 0; hp < 2; ++hp) {
        int h = wv * 2 + hp;
        f32x4 acc0 = {0.f, 0.f, 0.f, 0.f}, acc1 = {0.f, 0.f, 0.f, 0.f};
#pragma unroll
        for (int kp = 0; kp < 2; ++kp) {
            f16x8 afr = {};
            if (l16 < 4) afr = *(const f16x8*)(&lds_cat[l16][h * 64 + kp * 32 + hi * 8]);
            f16x8 bf0 = *(const f16x8*)(Wpf + (size_t)(((h * 2 + 0) * 2 + kp) * 64 + l) * 8);
            f16x8 bf1 = *(const f16x8*)(Wpf + (size_t)(((h * 2 + 1) * 2 + kp) * 64 + l) * 8);
            acc0 = __builtin_amdgcn_mfma_f32_16x16x32_f16(afr, bf0, acc0, 0, 0, 0);
            acc1 = __builtin_amdgcn_mfma_f32_16x16x32_f16(afr, bf1, acc1, 0, 0, 0);
        }
        if (hi == 0) {   // C rows 0..3 live on quad 0
            float pb0 = Pb[h * 32 + l16],        pb1 = Pb[h * 32 + 16 + l16];
            float fb0 = final_bias[h * 32 + l16], fb1 = final_bias[h * 32 + 16 + l16];
#pragma unroll
            for (int r = 0; r < 4; ++r) {
                int row = n0 + r;
                float g = gate_lds[r][h];
                out[(size_t)row * 256 + h * 32 + l16]      = fmaf(acc0[r] + pb0, g, fb0);
                out[(size_t)row * 256 + h * 32 + 16 + l16] = fmaf(acc1[r] + pb1, g, fb1);
            }
        }
    }
}

extern "C" void kernel_launch(void* const* d_in, const int* in_sizes, int n_in,
                              void* d_out, int out_size, void* d_ws, size_t ws_size,
                              hipStream_t stream) {
    const float* inp         = (const float*)d_in[0];
    const float* W_value     = (const float*)d_in[2];
    const float* W_relation  = (const float*)d_in[3];
    const float* deprel_emb  = (const float*)d_in[4];
    const float* deparc_emb  = (const float*)d_in[5];
    const float* w_src       = (const float*)d_in[6];
    const float* w_tgt       = (const float*)d_in[7];
    const float* w_rel       = (const float*)d_in[8];
    const float* fpw         = (const float*)d_in[9];
    const float* fpb         = (const float*)d_in[10];
    const float* neighbor_w  = (const float*)d_in[11];
    const float* neighbor_b  = (const float*)d_in[12];
    const float* gate_w      = (const float*)d_in[13];
    const float* gate_b      = (const float*)d_in[14];
    const float* final_bias  = (const float*)d_in[15];
    const int*   edge_index  = (const int*)d_in[16];
    const int*   deprel_edge = (const int*)d_in[17];
    const int*   deparc_edge = (const int*)d_in[18];
    const int* srcArr = edge_index;
    const int* tgtArr = edge_index + N_EDGES;
    float* out = (float*)d_out;

    // workspace carve (all offsets 16B-aligned)
    __half* valh = (__half*)d_ws;                                 // 10.24 MB
    unsigned short* Btf = (unsigned short*)(valh + 5120000);      // 160 KB
    float* bg2 = (float*)(Btf + 81920);                           // 8
    float* vs = bg2 + 8;
    float* vt = vs + 160000;
    float* g1 = vt + 160000;
    float* g2 = g1 + 160000;
    float* SA = g2 + 160000;                                      // 400
    float* SB = SA + 400;                                         // 32
    float* SAB = SB + 32;                                         // 1600 (200x8 combined)
    int* cnts = (int*)(SAB + 1600);                               // 160,000
    int* rowptr = cnts + 160000;                                  // 20,004 (padded)
    int* eidx = rowptr + 20004;                                   // 160,000 packed ints
    __half* Wpf = (__half*)(eidx + 160000);                       // 32 KB
    int* rss = (int*)(Wpf + 16384);                               // 640 (range,slice) sums
    int* cur = rss + 640;                                         // 20,000 working rowptr copy

    k_pre<<<914, 256, 0, stream>>>(W_value, neighbor_w, neighbor_b,
                                   w_src, w_tgt, gate_w, Btf, bg2,
                                   W_relation, w_rel, deprel_emb, deparc_emb,
                                   SA, SB, SAB, tgtArr, cnts, fpw, Wpf, rss);
    k_mid<<<1330, 256, 0, stream>>>(inp, Btf, bg2, valh, vs, vt, g1, g2, cnts, rss,
                                    rowptr, cur);
    k_fill<<<(N_EDGES / 4 + 255) / 256, 256, 0, stream>>>(srcArr, tgtArr, deprel_edge,
                                                          deparc_edge, cur, eidx);
    k_agg<<<N_NODES / 4, 256, 0, stream>>>(valh, vs, vt, SAB, g2, g1, gate_b,
                                           rowptr, eidx, Wpf, fpb, final_bias, out);
}